// Round 8
// baseline (72.155 us; speedup 1.0000x reference)
//
#include <hip/hip_runtime.h>
#include <math.h>

#define BB 4
#define RR 1024
#define NN 100
#define NROI (BB * RR)

// d_ws float layout:
//   GT tables (SoA per batch): ws[(b*18 + f)*NN + n], f in 0..17:
//     0 gx, 1 gy, 2 zlo, 3 zhi, 4 rb, 5 cos, 6 sin, 7 hx, 8 hy, 9 vol,
//     10..13 corner_x[0..3], 14..17 corner_y[0..3]
//   ROI table (AoS): ws[ROI_OFF + r*20 + f], same field order (18 used, pad 20)
#define GT_F (18 * NN)
#define ROI_OFF (BB * GT_F)

// packed best: high 32 = float bits of IoU (>=0, monotone), low 32 = ~gt_idx
// => u64 max picks highest IoU; exact tie -> smallest gt index (argmax-first).
#define INIT_PACK 0x00000000FFFFFFFFull

// corner i sign conv. matches reference lxs=[.5,-.5,-.5,.5], lys=[.5,.5,-.5,-.5]
__device__ __forceinline__ void corner_of(int i, float cx0, float cy0, float dx, float dy,
                                          float c, float s, float& X, float& Y) {
    float sx = (i == 0 || i == 3) ? 0.5f : -0.5f;
    float sy = (i <= 1) ? 0.5f : -0.5f;
    float lx = sx * dx, ly = sy * dy;
    X = cx0 + lx * c - ly * s;
    Y = cy0 + lx * s + ly * c;
}

// ---- K1: per-entity precompute (400 GTs + 4096 ROIs), once per launch ----
__global__ __launch_bounds__(256) void precompute_kernel(
    const float* __restrict__ rois, const float* __restrict__ gts,
    float* __restrict__ ws)
{
    int t = blockIdx.x * blockDim.x + threadIdx.x;
    if (t < BB * NN) {
        int b = t / NN, n = t - b * NN;
        const float4* gp = (const float4*)(gts + t * 8);
        float4 g0 = gp[0];                 // x,y,z,dx
        float4 g1 = gp[1];                 // dy,dz,heading,label
        float gx = g0.x, gy = g0.y, gz = g0.z, gdx = g0.w;
        float gdy = g1.x, gdz = g1.y, gang = g1.z;
        float c = cosf(gang), s = sinf(gang);
        float* T = ws + b * GT_F;
        T[0 * NN + n] = gx;
        T[1 * NN + n] = gy;
        T[2 * NN + n] = gz - gdz * 0.5f;
        T[3 * NN + n] = gz + gdz * 0.5f;
        T[4 * NN + n] = 0.5f * sqrtf(gdx * gdx + gdy * gdy);
        T[5 * NN + n] = c;
        T[6 * NN + n] = s;
        T[7 * NN + n] = gdx * 0.5f + 1e-5f;
        T[8 * NN + n] = gdy * 0.5f + 1e-5f;
        T[9 * NN + n] = gdx * gdy * gdz;
#pragma unroll
        for (int i = 0; i < 4; i++) {
            float X, Y;
            corner_of(i, gx, gy, gdx, gdy, c, s, X, Y);
            T[(10 + i) * NN + n] = X;
            T[(14 + i) * NN + n] = Y;
        }
    } else if (t < BB * NN + NROI) {
        int r = t - BB * NN;
        const float* A = rois + r * 7;
        float ax = A[0], ay = A[1], az = A[2];
        float adx = A[3], ady = A[4], adz = A[5], aang = A[6];
        float c = cosf(aang), s = sinf(aang);
        float* Rt = ws + ROI_OFF + r * 20;
        Rt[0] = ax; Rt[1] = ay;
        Rt[2] = az - adz * 0.5f;
        Rt[3] = az + adz * 0.5f;
        Rt[4] = 0.5f * sqrtf(adx * adx + ady * ady);
        Rt[5] = c; Rt[6] = s;
        Rt[7] = adx * 0.5f + 1e-5f;
        Rt[8] = ady * 0.5f + 1e-5f;
        Rt[9] = adx * ady * adz;
#pragma unroll
        for (int i = 0; i < 4; i++) {
            float X, Y;
            corner_of(i, ax, ay, adx, ady, c, s, X, Y);
            Rt[10 + i] = X;
            Rt[14 + i] = Y;
        }
    }
}

// ---- K2: one wave per ROI; no LDS, no __syncthreads, no sin/cos ----
__global__ __launch_bounds__(256) void eval_kernel(
    const float* __restrict__ rois,   // (B,R,7)
    const int*   __restrict__ labels, // (B,R)
    const float* __restrict__ gts,    // (B,N,8)
    const float* __restrict__ ws,     // precomputed tables
    float*       __restrict__ out)
{
    const int r    = (int)((blockIdx.x * blockDim.x + threadIdx.x) >> 6);
    const int lane = threadIdx.x & 63;
    if (r >= NROI) return;
    const int b = r >> 10;
    const float* T  = ws + b * GT_F;
    const float* Rt = ws + ROI_OFF + r * 20;

    // ROI params: broadcast loads (few cache lines)
    const float ax = Rt[0], ay = Rt[1], azlo = Rt[2], azhi = Rt[3], ara = Rt[4];
    const float acs = Rt[5], asn = Rt[6], ahx = Rt[7], ahy = Rt[8], va = Rt[9];

    // ---- cheap reject: lane n tests GT n; SoA gathers are fully coalesced ----
    unsigned long long m0, m1;
    {
        unsigned long long mm[2];
#pragma unroll
        for (int it = 0; it < 2; it++) {
            int n = it * 64 + lane;
            bool pass = false;
            if (n < NN) {
                float oh = fminf(azhi, T[3 * NN + n]) - fmaxf(azlo, T[2 * NN + n]);
                float dxc = ax - T[0 * NN + n], dyc = ay - T[1 * NN + n];
                float rr = ara + T[4 * NN + n];
                pass = (oh > 0.0f) && (dxc * dxc + dyc * dyc <= rr * rr);
            }
            mm[it] = __ballot(pass);
        }
        m0 = mm[0]; m1 = mm[1];
    }

    const int half = lane >> 5;
    const int l32  = lane & 31;
    unsigned long long best = INIT_PACK;

    // ---- dense eval: two survivors per iteration (one per half-wave) ----
    while (m0 | m1) {
        int na, nb = -1;
        if (m0) { na = __ffsll(m0) - 1;      m0 &= m0 - 1; }
        else    { na = __ffsll(m1) - 1 + 64; m1 &= m1 - 1; }
        if (m0)      { nb = __ffsll(m0) - 1;      m0 &= m0 - 1; }
        else if (m1) { nb = __ffsll(m1) - 1 + 64; m1 &= m1 - 1; }

        const int  myN    = half ? nb : na;
        const bool active = (myN >= 0);
        const int  nn     = active ? myN : 0;    // half-broadcast reads below
        float gx  = T[0 * NN + nn], gy  = T[1 * NN + nn];
        float bcs = T[5 * NN + nn], bsn = T[6 * NN + nn];
        float bhx = T[7 * NN + nn], bhy = T[8 * NN + nn];

        // my candidate vertex (lane slot = reference slot ordering)
        float ppx = 0.0f, ppy = 0.0f;
        bool val = false;
        if (l32 < 4) {                        // corners of A inside B
            ppx = Rt[10 + l32]; ppy = Rt[14 + l32];
            float qx = ppx - gx, qy = ppy - gy;
            float lx = qx * bcs + qy * bsn;
            float ly = -qx * bsn + qy * bcs;
            val = (fabsf(lx) <= bhx) && (fabsf(ly) <= bhy);
        } else if (l32 < 8) {                 // corners of B inside A
            int i4 = l32 - 4;
            ppx = T[(10 + i4) * NN + nn]; ppy = T[(14 + i4) * NN + nn];
            float qx = ppx - ax, qy = ppy - ay;
            float lx = qx * acs + qy * asn;
            float ly = -qx * asn + qy * acs;
            val = (fabsf(lx) <= ahx) && (fabsf(ly) <= ahy);
        } else if (l32 < 24) {                // edge ii of A x edge jj of B
            int e = l32 - 8, ii = e >> 2, jj = e & 3;
            float a1x = Rt[10 + ii],          a1y = Rt[14 + ii];
            float a2x = Rt[10 + ((ii+1)&3)],  a2y = Rt[14 + ((ii+1)&3)];
            float b1x = T[(10 + jj) * NN + nn],        b1y = T[(14 + jj) * NN + nn];
            float b2x = T[(10 + ((jj+1)&3)) * NN + nn], b2y = T[(14 + ((jj+1)&3)) * NN + nn];
            float d1x = a2x - a1x, d1y = a2y - a1y;
            float d2x = b2x - b1x, d2y = b2y - b1y;
            float denom = d1x * d2y - d1y * d2x;
            float fx = b1x - a1x, fy = b1y - a1y;
            float safe = (fabsf(denom) > 1e-8f) ? denom : 1e-8f;
            float t = (fx * d2y - fy * d2x) / safe;
            float u = (fx * d1y - fy * d1x) / safe;
            ppx = a1x + t * d1x;
            ppy = a1y + t * d1y;
            val = (fabsf(denom) > 1e-8f) && (t >= 0.0f) && (t <= 1.0f) && (u >= 0.0f) && (u <= 1.0f);
        }
        val = val && active;

        unsigned long long bm = __ballot(val);
        unsigned gm = half ? (unsigned)(bm >> 32) : (unsigned)(bm & 0xFFFFFFFFull);
        int nv = __popc(gm);

        float inter_bev = 0.0f;
        if (nv >= 3) {   // half-uniform branch; width-32 shuffles read own half only
            float sx = val ? ppx : 0.0f;
            float sy = val ? ppy : 0.0f;
#pragma unroll
            for (int off = 16; off; off >>= 1) {
                sx += __shfl_xor(sx, off, 32);
                sy += __shfl_xor(sy, off, 32);
            }
            float cx = sx / (float)nv, cy = sy / (float)nv;

            float myAng = val ? atan2f(ppy - cy, ppx - cx) : 1e9f;

            // successor in (angle, index) order, index-only tracking;
            // ascending j + strict < == reference stable-argsort tie rules
            float sAng = 1e30f; int sIdx = 0; bool found = false;
            float gAng = 1e30f; int gIdx = 0;
#pragma unroll
            for (int j = 0; j < 24; j++) {
                float aj = __shfl(myAng, j, 32);
                if (aj < 1e8f) {
                    bool greater = (aj > myAng) || (aj == myAng && j > l32);
                    if (greater && aj < sAng) { sAng = aj; sIdx = j; found = true; }
                    if (aj < gAng) { gAng = aj; gIdx = j; }
                }
            }
            int qi = found ? sIdx : gIdx;
            float qx = __shfl(ppx, qi, 32);
            float qy = __shfl(ppy, qi, 32);
            float contrib = val ? (ppx * qy - qx * ppy) : 0.0f;
#pragma unroll
            for (int off = 16; off; off >>= 1)
                contrib += __shfl_xor(contrib, off, 32);
            inter_bev = 0.5f * fabsf(contrib);
        }

        if (active) {
            float oh = fminf(azhi, T[3 * NN + nn]) - fmaxf(azlo, T[2 * NN + nn]); // >0 by cheap pass
            float inter = inter_bev * oh;
            float v = inter / fmaxf(va + T[9 * NN + nn] - inter, 1e-6f);
            unsigned long long packed =
                ((unsigned long long)__float_as_uint(v) << 32) | (unsigned)(~(unsigned)myN);
            best = (packed > best) ? packed : best;
        }
    }

    // merge the two halves
    {
        unsigned long long other = __shfl(best, lane ^ 32, 64);
        best = (other > best) ? other : best;
    }

    float mo = __uint_as_float((unsigned)(best >> 32));
    int besti = (int)(~(unsigned)(best & 0xFFFFFFFFu));

    // ---- distributed output writes ----
    float* out_rois = out;                    // NROI*7
    float* out_gor  = out + NROI * 7;         // NROI*8
    float* out_max  = out_gor + NROI * 8;     // NROI
    float* out_lab  = out_max + NROI;         // NROI
    float* out_msk  = out_lab + NROI;         // NROI

    if (lane < 7) {
        out_rois[r * 7 + lane] = rois[r * 7 + lane];
    } else if (lane < 15) {
        int k = lane - 7;
        out_gor[r * 8 + k] = gts[(b * NN + besti) * 8 + k];
    } else if (lane == 15) {
        out_max[r] = mo;
    } else if (lane == 16) {
        out_lab[r] = (float)labels[r];
    } else if (lane == 17) {
        out_msk[r] = (mo > 0.55f) ? 1.0f : 0.0f;
    }
}

extern "C" void kernel_launch(void* const* d_in, const int* in_sizes, int n_in,
                              void* d_out, int out_size, void* d_ws, size_t ws_size,
                              hipStream_t stream) {
    const float* rois   = (const float*)d_in[0];  // (4,1024,7) f32
    const int*   labels = (const int*)d_in[1];    // (4,1024) i32
    const float* gts    = (const float*)d_in[2];  // (4,100,8) f32
    float* out = (float*)d_out;
    float* ws  = (float*)d_ws;

    // K1: 400 GT + 4096 ROI precompute entries
    int k1_threads = BB * NN + NROI;
    hipLaunchKernelGGL(precompute_kernel, dim3((k1_threads + 255) / 256), dim3(256), 0, stream,
                       rois, gts, ws);
    // K2: one wave per ROI = 4096 waves = 1024 blocks x 256 threads
    hipLaunchKernelGGL(eval_kernel, dim3(NROI / 4), dim3(256), 0, stream,
                       rois, labels, gts, ws, out);
}

// Round 9
// 67.096 us; speedup vs baseline: 1.0754x; 1.0754x over previous
//
#include <hip/hip_runtime.h>
#include <math.h>

#define BB 4
#define RR 1024
#define NN 100
#define NROI (BB * RR)
#define RPB 4                      // ROIs per block (small => 4 blocks/CU => latency hiding)
#define PPB (RPB * NN)             // 400 pairs per block
#define NBLK (NROI / RPB)          // 1024 blocks

// packed best: high 32 = float bits of IoU (>=0, monotone), low 32 = ~gt_idx
// => atomicMax picks highest IoU; on exact tie, smallest gt index (argmax-first semantics).
#define INIT_PACK 0x00000000FFFFFFFFull

// corner i of a rect; sign conv. matches reference lxs=[.5,-.5,-.5,.5], lys=[.5,.5,-.5,-.5]
__device__ __forceinline__ void corner_of(int i, float cx0, float cy0, float dx, float dy,
                                          float c, float s, float& X, float& Y) {
    float sx = (i == 0 || i == 3) ? 0.5f : -0.5f;
    float sy = (i <= 1) ? 0.5f : -0.5f;
    float lx = sx * dx, ly = sy * dy;
    X = cx0 + lx * c - ly * s;
    Y = cy0 + lx * s + ly * c;
}

// Single-dispatch fused kernel (session-best structure, R5 == 67.7 us bench).
// Block owns 4 ROIs of one batch (1024%4==0 -> no batch straddle).
// Phase A: cheap z/circle reject over 400 pairs -> LDS worklist (compaction).
// Phase B: one surviving pair per 32-lane group; 24 polygon vertex candidates
//          live one-per-lane (no local arrays -> no scratch-spill, the R2/R3
//          pathology). Successor search: 24 angle-broadcast shuffles tracking
//          INDEX only, then 2 shuffles fetch the successor point.
// Phase C: 4 threads write the five outputs.
__global__ __launch_bounds__(256) void sampling_target_fused(
    const float* __restrict__ rois,   // (B,R,7)
    const int*   __restrict__ labels, // (B,R)
    const float* __restrict__ gts,    // (B,N,8)
    float*       __restrict__ out)
{
    __shared__ float s_gts[NN * 9];            // stride 9 (2-way-max bank aliasing: free)
    __shared__ float s_rois[RPB * 7];
    __shared__ int   s_list[PPB];
    __shared__ int   s_cnt;
    __shared__ unsigned long long s_best[RPB];

    const int tid = threadIdx.x;
    const int roi0 = blockIdx.x * RPB;
    const int b = roi0 >> 10;                  // RR = 1024

    // ---- stage ----
    for (int i = tid; i < NN * 8; i += 256)
        s_gts[(i >> 3) * 9 + (i & 7)] = gts[b * NN * 8 + i];
    if (tid < RPB * 7) s_rois[tid] = rois[roi0 * 7 + tid];
    if (tid < RPB) s_best[tid] = INIT_PACK;
    if (tid == 0) s_cnt = 0;
    __syncthreads();

    // ---- Phase A: cheap reject + compaction (400 pairs, <2 iters/thread) ----
    for (int p = tid; p < PPB; p += 256) {
        int rl = p / NN;
        int n = p - rl * NN;
        const float* A = &s_rois[rl * 7];
        const float* G = &s_gts[n * 9];
        float oh = fminf(A[2] + A[5] * 0.5f, G[2] + G[5] * 0.5f)
                 - fmaxf(A[2] - A[5] * 0.5f, G[2] - G[5] * 0.5f);
        float dxc = A[0] - G[0], dyc = A[1] - G[1];
        float ra = 0.5f * sqrtf(A[3] * A[3] + A[4] * A[4]);
        float rb = 0.5f * sqrtf(G[3] * G[3] + G[4] * G[4]);
        float rr = ra + rb;
        if (oh > 0.0f && dxc * dxc + dyc * dyc <= rr * rr) {
            int pos = atomicAdd(&s_cnt, 1);
            s_list[pos] = p;   // capacity PPB: cannot overflow
        }
    }
    __syncthreads();

    // ---- Phase B: lane-parallel exact IoU, one pair per 32-lane group ----
    const int cnt = s_cnt;                     // ~7 expected => ~1 iter/group
    const int g = tid >> 5;                    // 8 groups per block
    const int lane = tid & 31;
    const int half = (tid >> 5) & 1;

    for (int i = g; i < cnt; i += 8) {
        int p = s_list[i];
        int rl = p / NN;
        int n = p - rl * NN;
        const float* A = &s_rois[rl * 7];      // group-broadcast LDS reads
        const float* G = &s_gts[n * 9];
        float ax = A[0], ay = A[1], az = A[2], adx = A[3], ady = A[4], adz = A[5], aang = A[6];
        float gx_ = G[0], gy_ = G[1], gz_ = G[2], gdx = G[3], gdy = G[4], gdz = G[5], gang = G[6];
        float acs = cosf(aang), asn = sinf(aang);
        float bcs = cosf(gang), bsn = sinf(gang);

        // my candidate vertex (lane -> reference slot k, same ordering)
        float ppx = 0.0f, ppy = 0.0f;
        bool val = false;
        if (lane < 4) {                        // corners of A, tested inside B
            corner_of(lane, ax, ay, adx, ady, acs, asn, ppx, ppy);
            float qx = ppx - gx_, qy = ppy - gy_;
            float lx = qx * bcs + qy * bsn;
            float ly = -qx * bsn + qy * bcs;
            val = (fabsf(lx) <= gdx * 0.5f + 1e-5f) && (fabsf(ly) <= gdy * 0.5f + 1e-5f);
        } else if (lane < 8) {                 // corners of B, tested inside A
            corner_of(lane - 4, gx_, gy_, gdx, gdy, bcs, bsn, ppx, ppy);
            float qx = ppx - ax, qy = ppy - ay;
            float lx = qx * acs + qy * asn;
            float ly = -qx * asn + qy * acs;
            val = (fabsf(lx) <= adx * 0.5f + 1e-5f) && (fabsf(ly) <= ady * 0.5f + 1e-5f);
        } else if (lane < 24) {                // edge i of A x edge j of B
            int e = lane - 8;
            int ii = e >> 2, jj = e & 3;
            float a1x, a1y, a2x, a2y, b1x, b1y, b2x, b2y;
            corner_of(ii, ax, ay, adx, ady, acs, asn, a1x, a1y);
            corner_of((ii + 1) & 3, ax, ay, adx, ady, acs, asn, a2x, a2y);
            corner_of(jj, gx_, gy_, gdx, gdy, bcs, bsn, b1x, b1y);
            corner_of((jj + 1) & 3, gx_, gy_, gdx, gdy, bcs, bsn, b2x, b2y);
            float d1x = a2x - a1x, d1y = a2y - a1y;
            float d2x = b2x - b1x, d2y = b2y - b1y;
            float denom = d1x * d2y - d1y * d2x;
            float fx = b1x - a1x, fy = b1y - a1y;
            float safe = (fabsf(denom) > 1e-8f) ? denom : 1e-8f;
            float t = (fx * d2y - fy * d2x) / safe;
            float u = (fx * d1y - fy * d1x) / safe;
            ppx = a1x + t * d1x;
            ppy = a1y + t * d1y;
            val = (fabsf(denom) > 1e-8f) && (t >= 0.0f) && (t <= 1.0f) && (u >= 0.0f) && (u <= 1.0f);
        }

        unsigned long long m = __ballot(val);
        unsigned gm = (unsigned)(half ? (m >> 32) : (m & 0xFFFFFFFFull));
        int nv = __popc(gm);

        float inter_bev = 0.0f;
        if (nv >= 3) {   // group-uniform branch; width-32 shuffles safe inside
            float sx = val ? ppx : 0.0f;
            float sy = val ? ppy : 0.0f;
#pragma unroll
            for (int off = 16; off; off >>= 1) {
                sx += __shfl_xor(sx, off, 32);
                sy += __shfl_xor(sy, off, 32);
            }
            float cx = sx / (float)nv, cy = sy / (float)nv;

            float myAng = val ? atan2f(ppy - cy, ppx - cx) : 1e9f;

            // successor in (angle, index) order, index-only tracking;
            // ascending j + strict < reproduces stable-argsort tie rules.
            float sAng = 1e30f; int sIdx = 0; bool found = false;
            float gAng = 1e30f; int gIdx = 0;
#pragma unroll
            for (int j = 0; j < 24; j++) {
                float aj = __shfl(myAng, j, 32);
                if (aj < 1e8f) {   // valid j only
                    bool greater = (aj > myAng) || (aj == myAng && j > lane);
                    if (greater && aj < sAng) { sAng = aj; sIdx = j; found = true; }
                    if (aj < gAng) { gAng = aj; gIdx = j; }
                }
            }
            int qi = found ? sIdx : gIdx;
            float qx = __shfl(ppx, qi, 32);
            float qy = __shfl(ppy, qi, 32);
            float contrib = val ? (ppx * qy - qx * ppy) : 0.0f;
#pragma unroll
            for (int off = 16; off; off >>= 1)
                contrib += __shfl_xor(contrib, off, 32);
            inter_bev = 0.5f * fabsf(contrib);
        }

        if (lane == 0) {
            float oh = fminf(az + adz * 0.5f, gz_ + gdz * 0.5f)
                     - fmaxf(az - adz * 0.5f, gz_ - gdz * 0.5f);   // >0 by Phase A
            float inter = inter_bev * oh;
            float va = adx * ady * adz;
            float vb = gdx * gdy * gdz;
            float v = inter / fmaxf(va + vb - inter, 1e-6f);
            unsigned long long packed =
                ((unsigned long long)__float_as_uint(v) << 32) | (unsigned)(~(unsigned)n);
            atomicMax(&s_best[rl], packed);
        }
    }
    __syncthreads();

    // ---- Phase C: outputs ----
    if (tid < RPB) {
        int r = roi0 + tid;
        unsigned long long packed = s_best[tid];
        float mo = __uint_as_float((unsigned)(packed >> 32));
        int besti = (int)(~(unsigned)(packed & 0xFFFFFFFFu));

        float* out_rois = out;                    // NROI*7
        float* out_gor  = out + NROI * 7;         // NROI*8
        float* out_max  = out_gor + NROI * 8;     // NROI
        float* out_lab  = out_max + NROI;         // NROI
        float* out_msk  = out_lab + NROI;         // NROI

#pragma unroll
        for (int k = 0; k < 7; k++) out_rois[r * 7 + k] = s_rois[tid * 7 + k];
#pragma unroll
        for (int k = 0; k < 8; k++) out_gor[r * 8 + k] = s_gts[besti * 9 + k];
        out_max[r] = mo;
        out_lab[r] = (float)labels[r];
        out_msk[r] = (mo > 0.55f) ? 1.0f : 0.0f;
    }
}

extern "C" void kernel_launch(void* const* d_in, const int* in_sizes, int n_in,
                              void* d_out, int out_size, void* d_ws, size_t ws_size,
                              hipStream_t stream) {
    const float* rois   = (const float*)d_in[0];  // (4,1024,7) f32
    const int*   labels = (const int*)d_in[1];    // (4,1024) i32
    const float* gts    = (const float*)d_in[2];  // (4,100,8) f32
    float* out = (float*)d_out;

    hipLaunchKernelGGL(sampling_target_fused, dim3(NBLK), dim3(256), 0, stream,
                       rois, labels, gts, out);
}